// Round 1
// baseline (3151.566 us; speedup 1.0000x reference)
//
#include <hip/hip_runtime.h>

#define N_NODES 50000
#define N_EDGES 800000
#define F_IN 768
#define H1 200
#define H2 20

// ---------------- degree kernels ----------------
__global__ __launch_bounds__(256) void k_degrees(const int* __restrict__ src,
                                                 const int* __restrict__ dst,
                                                 float* __restrict__ deg_o,
                                                 float* __restrict__ deg_i) {
  int i = blockIdx.x * 256 + threadIdx.x;
  if (i < N_EDGES) {
    atomicAdd(&deg_o[src[i]], 1.0f);
    atomicAdd(&deg_i[dst[i]], 1.0f);
  }
}

__global__ __launch_bounds__(256) void k_finalize_deg(float* __restrict__ deg_o,
                                                      float* __restrict__ deg_i) {
  int i = blockIdx.x * 256 + threadIdx.x;
  if (i < N_NODES) {
    deg_o[i] = rsqrtf(fmaxf(deg_o[i], 1.0f));  // becomes dinv_out
    deg_i[i] = rsqrtf(fmaxf(deg_i[i], 1.0f));  // becomes dinv_in
  }
}

// ---------------- GEMM1: h = (feat * dinv_out[:,None]) @ W1 ----------------
// M=50000, K=768, N=200. fp32 vector-ALU tiled GEMM.
// BM=128, BN=64, BK=16; 256 threads; 8x4 micro-tile per thread.
constexpr int BM = 128, BN = 64, BK = 16;

__global__ __launch_bounds__(256) void k_gemm1(const float* __restrict__ A,  // [N,768]
                                               const float* __restrict__ B,  // [768,200]
                                               const float* __restrict__ dinv_out,
                                               float* __restrict__ H) {      // [N,200]
  __shared__ float As[BK][BM + 4];  // +4 pad keeps 16B alignment, breaks bank conflicts
  __shared__ float Bs[BK][BN];
  const int bm = blockIdx.x * BM;
  const int bn = blockIdx.y * BN;
  const int t = threadIdx.x;
  const int tx = t & 15, ty = t >> 4;

  float acc[8][4] = {};

  for (int k0 = 0; k0 < F_IN; k0 += BK) {
    // A tile: 128x16 = 2048 floats, 2 float4 per thread (same row, kk 0..7 / 8..15)
#pragma unroll
    for (int l = 0; l < 2; ++l) {
      int e = t * 8 + l * 4;
      int row = e >> 4;
      int kk = e & 15;
      float4 v = make_float4(0.f, 0.f, 0.f, 0.f);
      int gr = bm + row;
      if (gr < N_NODES) v = *(const float4*)&A[gr * F_IN + k0 + kk];
      As[kk + 0][row] = v.x;
      As[kk + 1][row] = v.y;
      As[kk + 2][row] = v.z;
      As[kk + 3][row] = v.w;
    }
    // B tile: 16x64 = 1024 floats, 1 float4 per thread
    {
      int e = t * 4;
      int kr = e >> 6;
      int n = e & 63;
      float4 v = make_float4(0.f, 0.f, 0.f, 0.f);
      if (bn + n < H1) v = *(const float4*)&B[(k0 + kr) * H1 + bn + n];
      *(float4*)&Bs[kr][n] = v;
    }
    __syncthreads();
#pragma unroll
    for (int k = 0; k < BK; ++k) {
      float a[8], b[4];
      *(float4*)&a[0] = *(const float4*)&As[k][ty * 8];
      *(float4*)&a[4] = *(const float4*)&As[k][ty * 8 + 4];
      *(float4*)&b[0] = *(const float4*)&Bs[k][tx * 4];
#pragma unroll
      for (int i = 0; i < 8; ++i)
#pragma unroll
        for (int j = 0; j < 4; ++j) acc[i][j] = fmaf(a[i], b[j], acc[i][j]);
    }
    __syncthreads();
  }

#pragma unroll
  for (int i = 0; i < 8; ++i) {
    int gr = bm + ty * 8 + i;
    if (gr >= N_NODES) continue;
    float s = dinv_out[gr];
    int gc = bn + tx * 4;
    if (gc < H1) {  // H1 % 4 == 0 so a float4 starting <200 fits entirely
      float4 r = make_float4(acc[i][0] * s, acc[i][1] * s, acc[i][2] * s, acc[i][3] * s);
      *(float4*)&H[gr * H1 + gc] = r;
    }
  }
}

// ---------------- edge scatter, layer 1 ----------------
// one thread per (edge, 4-dim chunk): 50 chunks per edge; lanes within an edge
// cover consecutive dims -> coalesced gather and coalesced atomics.
__global__ __launch_bounds__(256) void k_scatter1(const int* __restrict__ src,
                                                  const int* __restrict__ dst,
                                                  const float* __restrict__ ew,
                                                  const float* __restrict__ H,
                                                  float* __restrict__ agg) {
  int gi = blockIdx.x * 256 + threadIdx.x;
  if (gi >= N_EDGES * (H1 / 4)) return;
  int e = gi / (H1 / 4);
  int c = gi % (H1 / 4);
  int s = src[e], d = dst[e];
  float w = ew[e];
  float4 v = *(const float4*)&H[s * H1 + c * 4];
  float* p = &agg[d * H1 + c * 4];
  atomicAdd(p + 0, v.x * w);
  atomicAdd(p + 1, v.y * w);
  atomicAdd(p + 2, v.z * w);
  atomicAdd(p + 3, v.w * w);
}

// ---------------- post layer1: t = relu(agg*dinv_in + b1) * dinv_out ----------------
__global__ __launch_bounds__(256) void k_post1(const float* __restrict__ agg,
                                               const float* __restrict__ dinv_in,
                                               const float* __restrict__ dinv_out,
                                               const float* __restrict__ b1,
                                               float* __restrict__ T) {
  int gi = blockIdx.x * 256 + threadIdx.x;
  if (gi >= N_NODES * (H1 / 4)) return;
  int i = gi / (H1 / 4);
  int c = gi % (H1 / 4);
  float di = dinv_in[i], dn = dinv_out[i];
  float4 v = *(const float4*)&agg[i * H1 + c * 4];
  float4 bb = *(const float4*)&b1[c * 4];
  float4 r;
  r.x = fmaxf(fmaf(v.x, di, bb.x), 0.f) * dn;
  r.y = fmaxf(fmaf(v.y, di, bb.y), 0.f) * dn;
  r.z = fmaxf(fmaf(v.z, di, bb.z), 0.f) * dn;
  r.w = fmaxf(fmaf(v.w, di, bb.w), 0.f) * dn;
  *(float4*)&T[i * H1 + c * 4] = r;
}

// ---------------- GEMM2: g = T @ W2, [50000,200]x[200,20] ----------------
// one thread per (node, 4-col chunk): 5 chunks per node.
__global__ __launch_bounds__(256) void k_gemm2(const float* __restrict__ T,
                                               const float* __restrict__ W2,
                                               float* __restrict__ G) {
  int gi = blockIdx.x * 256 + threadIdx.x;
  if (gi >= N_NODES * (H2 / 4)) return;
  int i = gi / (H2 / 4);
  int q = gi % (H2 / 4);
  const float* trow = &T[i * H1];
  float4 acc = make_float4(0.f, 0.f, 0.f, 0.f);
  for (int k = 0; k < H1; k += 4) {
    float4 a = *(const float4*)&trow[k];
#pragma unroll
    for (int kk = 0; kk < 4; ++kk) {
      float av = (&a.x)[kk];
      float4 w = *(const float4*)&W2[(k + kk) * H2 + q * 4];
      acc.x = fmaf(av, w.x, acc.x);
      acc.y = fmaf(av, w.y, acc.y);
      acc.z = fmaf(av, w.z, acc.z);
      acc.w = fmaf(av, w.w, acc.w);
    }
  }
  *(float4*)&G[i * H2 + q * 4] = acc;
}

// ---------------- edge scatter, layer 2 ----------------
__global__ __launch_bounds__(256) void k_scatter2(const int* __restrict__ src,
                                                  const int* __restrict__ dst,
                                                  const float* __restrict__ ew,
                                                  const float* __restrict__ G,
                                                  float* __restrict__ agg2) {
  int gi = blockIdx.x * 256 + threadIdx.x;
  if (gi >= N_EDGES * (H2 / 4)) return;
  int e = gi / (H2 / 4);
  int c = gi % (H2 / 4);
  int s = src[e], d = dst[e];
  float w = ew[e];
  float4 v = *(const float4*)&G[s * H2 + c * 4];
  float* p = &agg2[d * H2 + c * 4];
  atomicAdd(p + 0, v.x * w);
  atomicAdd(p + 1, v.y * w);
  atomicAdd(p + 2, v.z * w);
  atomicAdd(p + 3, v.w * w);
}

// ---------------- final: out = agg2*dinv_in + b2 ----------------
__global__ __launch_bounds__(256) void k_final(const float* __restrict__ agg2,
                                               const float* __restrict__ dinv_in,
                                               const float* __restrict__ b2,
                                               float* __restrict__ out) {
  int gi = blockIdx.x * 256 + threadIdx.x;
  if (gi >= N_NODES * (H2 / 4)) return;
  int i = gi / (H2 / 4);
  int c = gi % (H2 / 4);
  float di = dinv_in[i];
  float4 v = *(const float4*)&agg2[i * H2 + c * 4];
  float4 bb = *(const float4*)&b2[c * 4];
  float4 r;
  r.x = fmaf(v.x, di, bb.x);
  r.y = fmaf(v.y, di, bb.y);
  r.z = fmaf(v.z, di, bb.z);
  r.w = fmaf(v.w, di, bb.w);
  *(float4*)&out[i * H2 + c * 4] = r;
}

extern "C" void kernel_launch(void* const* d_in, const int* in_sizes, int n_in,
                              void* d_out, int out_size, void* d_ws, size_t ws_size,
                              hipStream_t stream) {
  const float* feature = (const float*)d_in[0];
  const int* src = (const int*)d_in[1];
  const int* dst = (const int*)d_in[2];
  const float* edge_w = (const float*)d_in[3];
  const float* W1 = (const float*)d_in[4];
  const float* b1 = (const float*)d_in[5];
  const float* W2 = (const float*)d_in[6];
  const float* b2 = (const float*)d_in[7];
  float* out = (float*)d_out;

  // workspace layout (floats):
  // [0,50000)           deg_out -> dinv_out
  // [50000,100000)      deg_in  -> dinv_in
  // [100000, 100000+10M)      agg1
  // [100000+10M, 100000+11M)  agg2
  // [100000+11M, 100000+21M)  h (GEMM1 out; reused as T after post1)
  // g2 (1M) reuses agg1's storage (dead after post1).
  float* ws = (float*)d_ws;
  float* deg_o = ws;
  float* deg_i = ws + 50000;
  float* agg1 = ws + 100000;
  float* agg2 = ws + 100000 + 10000000;
  float* h = ws + 100000 + 11000000;
  float* g2 = agg1;  // reuse

  // zero: degrees + agg1 + agg2 (contiguous prefix of 11.1M floats)
  hipMemsetAsync(ws, 0, (size_t)(100000 + 11000000) * sizeof(float), stream);

  k_degrees<<<(N_EDGES + 255) / 256, 256, 0, stream>>>(src, dst, deg_o, deg_i);
  k_finalize_deg<<<(N_NODES + 255) / 256, 256, 0, stream>>>(deg_o, deg_i);

  dim3 g1((N_NODES + BM - 1) / BM, (H1 + BN - 1) / BN);
  k_gemm1<<<g1, 256, 0, stream>>>(feature, W1, deg_o, h);

  k_scatter1<<<(N_EDGES * (H1 / 4) + 255) / 256, 256, 0, stream>>>(src, dst, edge_w, h, agg1);
  k_post1<<<(N_NODES * (H1 / 4) + 255) / 256, 256, 0, stream>>>(agg1, deg_i, deg_o, b1, h);
  k_gemm2<<<(N_NODES * (H2 / 4) + 255) / 256, 256, 0, stream>>>(h, W2, g2);
  k_scatter2<<<(N_EDGES * (H2 / 4) + 255) / 256, 256, 0, stream>>>(src, dst, edge_w, g2, agg2);
  k_final<<<(N_NODES * (H2 / 4) + 255) / 256, 256, 0, stream>>>(agg2, deg_i, b2, out);
}

// Round 2
// 716.720 us; speedup vs baseline: 4.3972x; 4.3972x over previous
//
#include <hip/hip_runtime.h>

#define N_NODES 50000
#define N_EDGES 800000
#define F_IN 768
#define H1 200
#define H2 20
#define NB_SCAN 196  // ceil(50000/256)

// ---------------------------------------------------------------------------
// Workspace layout (units of 4 bytes):
//   0        cnt_dst   int[50000]   (zeroed)
//   50000    cnt_src   int[50000]   (zeroed)
//   100000   cursor    int[50000]   (zeroed)
//   150000   partials  int[256]
//   150256   row_start int[50000]
//   200256   dinv_in   f32[50000]
//   250256   dinv_out  f32[50000]
//   300256   src_s     int[800000]   (dst-sorted src ids)
//   1100256  w_s       f32[800000]   (dst-sorted edge weights)
//   1900256  h         f32[10000000] (GEMM1 output, [N,200])
//   11900256 g2        f32[1000000]  ([N,20])
// total 12.9M * 4B = 51.6 MB
// ---------------------------------------------------------------------------

// ---------------- histogram of degrees (int atomics, 1.6M total) -----------
__global__ __launch_bounds__(256) void k_count(const int* __restrict__ src,
                                               const int* __restrict__ dst,
                                               int* __restrict__ cnt_src,
                                               int* __restrict__ cnt_dst) {
  int i = blockIdx.x * 256 + threadIdx.x;
  if (i < N_EDGES) {
    atomicAdd(&cnt_src[src[i]], 1);
    atomicAdd(&cnt_dst[dst[i]], 1);
  }
}

// ---------------- 2-level exclusive scan of cnt_dst -> row_start -----------
__global__ __launch_bounds__(256) void k_scan_block(const int* __restrict__ cnt_dst,
                                                    int* __restrict__ row_start,
                                                    int* __restrict__ partials) {
  __shared__ int sm[256];
  int i = blockIdx.x * 256 + threadIdx.x;
  int v = (i < N_NODES) ? cnt_dst[i] : 0;
  sm[threadIdx.x] = v;
  __syncthreads();
#pragma unroll
  for (int off = 1; off < 256; off <<= 1) {
    int t = (threadIdx.x >= off) ? sm[threadIdx.x - off] : 0;
    __syncthreads();
    sm[threadIdx.x] += t;
    __syncthreads();
  }
  if (i < N_NODES) row_start[i] = sm[threadIdx.x] - v;  // exclusive
  if (threadIdx.x == 255) partials[blockIdx.x] = sm[255];
}

__global__ __launch_bounds__(256) void k_scan_partials(int* __restrict__ partials) {
  __shared__ int sm[256];
  int v = (threadIdx.x < NB_SCAN) ? partials[threadIdx.x] : 0;
  sm[threadIdx.x] = v;
  __syncthreads();
#pragma unroll
  for (int off = 1; off < 256; off <<= 1) {
    int t = (threadIdx.x >= off) ? sm[threadIdx.x - off] : 0;
    __syncthreads();
    sm[threadIdx.x] += t;
    __syncthreads();
  }
  partials[threadIdx.x] = sm[threadIdx.x] - v;  // exclusive scan of partials
}

__global__ __launch_bounds__(256) void k_scan_add(const int* __restrict__ cnt_dst,
                                                  const int* __restrict__ cnt_src,
                                                  const int* __restrict__ partials,
                                                  int* __restrict__ row_start,
                                                  float* __restrict__ dinv_in,
                                                  float* __restrict__ dinv_out) {
  int i = blockIdx.x * 256 + threadIdx.x;
  if (i < N_NODES) {
    row_start[i] += partials[blockIdx.x];
    dinv_in[i] = rsqrtf(fmaxf((float)cnt_dst[i], 1.f));
    dinv_out[i] = rsqrtf(fmaxf((float)cnt_src[i], 1.f));
  }
}

// ---------------- fill dst-sorted edge arrays -------------------------------
__global__ __launch_bounds__(256) void k_fill(const int* __restrict__ src,
                                              const int* __restrict__ dst,
                                              const float* __restrict__ ew,
                                              const int* __restrict__ row_start,
                                              int* __restrict__ cursor,
                                              int* __restrict__ src_s,
                                              float* __restrict__ w_s) {
  int e = blockIdx.x * 256 + threadIdx.x;
  if (e < N_EDGES) {
    int d = dst[e];
    int pos = atomicAdd(&cursor[d], 1);
    int idx = row_start[d] + pos;
    src_s[idx] = src[e];
    w_s[idx] = ew[e];
  }
}

// ---------------- GEMM1: h = (feat * dinv_out[:,None]) @ W1 ----------------
constexpr int BM = 128, BN = 64, BK = 16;

__global__ __launch_bounds__(256) void k_gemm1(const float* __restrict__ A,  // [N,768]
                                               const float* __restrict__ B,  // [768,200]
                                               const float* __restrict__ dinv_out,
                                               float* __restrict__ H) {      // [N,200]
  __shared__ float As[BK][BM + 4];
  __shared__ float Bs[BK][BN];
  const int bm = blockIdx.x * BM;
  const int bn = blockIdx.y * BN;
  const int t = threadIdx.x;
  const int tx = t & 15, ty = t >> 4;

  float acc[8][4] = {};

  for (int k0 = 0; k0 < F_IN; k0 += BK) {
#pragma unroll
    for (int l = 0; l < 2; ++l) {
      int e = t * 8 + l * 4;
      int row = e >> 4;
      int kk = e & 15;
      float4 v = make_float4(0.f, 0.f, 0.f, 0.f);
      int gr = bm + row;
      if (gr < N_NODES) v = *(const float4*)&A[gr * F_IN + k0 + kk];
      As[kk + 0][row] = v.x;
      As[kk + 1][row] = v.y;
      As[kk + 2][row] = v.z;
      As[kk + 3][row] = v.w;
    }
    {
      int e = t * 4;
      int kr = e >> 6;
      int n = e & 63;
      float4 v = make_float4(0.f, 0.f, 0.f, 0.f);
      if (bn + n < H1) v = *(const float4*)&B[(k0 + kr) * H1 + bn + n];
      *(float4*)&Bs[kr][n] = v;
    }
    __syncthreads();
#pragma unroll
    for (int k = 0; k < BK; ++k) {
      float a[8], b[4];
      *(float4*)&a[0] = *(const float4*)&As[k][ty * 8];
      *(float4*)&a[4] = *(const float4*)&As[k][ty * 8 + 4];
      *(float4*)&b[0] = *(const float4*)&Bs[k][tx * 4];
#pragma unroll
      for (int i = 0; i < 8; ++i)
#pragma unroll
        for (int j = 0; j < 4; ++j) acc[i][j] = fmaf(a[i], b[j], acc[i][j]);
    }
    __syncthreads();
  }

#pragma unroll
  for (int i = 0; i < 8; ++i) {
    int gr = bm + ty * 8 + i;
    if (gr >= N_NODES) continue;
    float s = dinv_out[gr];
    int gc = bn + tx * 4;
    if (gc < H1) {
      float4 r = make_float4(acc[i][0] * s, acc[i][1] * s, acc[i][2] * s, acc[i][3] * s);
      *(float4*)&H[gr * H1 + gc] = r;
    }
  }
}

// ---------------- layer1 fused: gather-agg + post + GEMM2 ------------------
// One 64-lane wave per node (4 waves/block, 50000 = 12500*4 exactly).
// Lanes 0..49 hold the 200-dim row as float4; gather h[src] rows coalesced
// (800B/edge), accumulate with 2-deep pipeline; relu/bias/norm in regs;
// stage T-row in LDS; lanes 0..19 compute the 20 GEMM2 outputs (W2 L1-hot).
__global__ __launch_bounds__(256) void k_layer1(
    const int* __restrict__ row_start, const int* __restrict__ cnt,
    const int* __restrict__ src_s, const float* __restrict__ w_s,
    const float* __restrict__ H, const float* __restrict__ dinv_in,
    const float* __restrict__ dinv_out, const float* __restrict__ b1,
    const float* __restrict__ W2, float* __restrict__ G) {
  __shared__ float Tsm[4][H1];
  const int wid = threadIdx.x >> 6;
  const int lane = threadIdx.x & 63;
  const int node = __builtin_amdgcn_readfirstlane(blockIdx.x * 4 + wid);
  const int start = __builtin_amdgcn_readfirstlane(row_start[node]);
  const int n = __builtin_amdgcn_readfirstlane(cnt[node]);
  const float4* __restrict__ Hv = (const float4*)H;
  const bool act = lane < (H1 / 4);
  float4 acc = make_float4(0.f, 0.f, 0.f, 0.f);

  int e = 0;
  for (; e + 2 <= n; e += 2) {
    int s0 = src_s[start + e];
    int s1 = src_s[start + e + 1];
    float w0 = w_s[start + e];
    float w1 = w_s[start + e + 1];
    if (act) {
      float4 v0 = Hv[s0 * (H1 / 4) + lane];
      float4 v1 = Hv[s1 * (H1 / 4) + lane];
      acc.x = fmaf(w0, v0.x, acc.x);
      acc.y = fmaf(w0, v0.y, acc.y);
      acc.z = fmaf(w0, v0.z, acc.z);
      acc.w = fmaf(w0, v0.w, acc.w);
      acc.x = fmaf(w1, v1.x, acc.x);
      acc.y = fmaf(w1, v1.y, acc.y);
      acc.z = fmaf(w1, v1.z, acc.z);
      acc.w = fmaf(w1, v1.w, acc.w);
    }
  }
  if (e < n) {
    int s0 = src_s[start + e];
    float w0 = w_s[start + e];
    if (act) {
      float4 v0 = Hv[s0 * (H1 / 4) + lane];
      acc.x = fmaf(w0, v0.x, acc.x);
      acc.y = fmaf(w0, v0.y, acc.y);
      acc.z = fmaf(w0, v0.z, acc.z);
      acc.w = fmaf(w0, v0.w, acc.w);
    }
  }

  if (act) {
    float di = dinv_in[node];
    float dn = dinv_out[node];
    float4 bb = ((const float4*)b1)[lane];
    float4 r;
    r.x = fmaxf(fmaf(acc.x, di, bb.x), 0.f) * dn;
    r.y = fmaxf(fmaf(acc.y, di, bb.y), 0.f) * dn;
    r.z = fmaxf(fmaf(acc.z, di, bb.z), 0.f) * dn;
    r.w = fmaxf(fmaf(acc.w, di, bb.w), 0.f) * dn;
    *(float4*)&Tsm[wid][lane * 4] = r;
  }
  __syncthreads();

  if (lane < H2) {
    float a = 0.f;
#pragma unroll 8
    for (int d = 0; d < H1; ++d) a = fmaf(Tsm[wid][d], W2[d * H2 + lane], a);
    G[node * H2 + lane] = a;
  }
}

// ---------------- layer2: gather-agg + bias (no atomics) -------------------
// one thread per (node, dim); g2 is 4MB -> L2-resident gather.
__global__ __launch_bounds__(256) void k_agg2_final(
    const int* __restrict__ row_start, const int* __restrict__ cnt,
    const int* __restrict__ src_s, const float* __restrict__ w_s,
    const float* __restrict__ G, const float* __restrict__ dinv_in,
    const float* __restrict__ b2, float* __restrict__ out) {
  int gi = blockIdx.x * 256 + threadIdx.x;
  if (gi >= N_NODES * H2) return;
  int node = gi / H2;
  int dim = gi % H2;
  int start = row_start[node];
  int n = cnt[node];
  float acc = 0.f;
  int e = 0;
  for (; e + 2 <= n; e += 2) {
    int s0 = src_s[start + e];
    int s1 = src_s[start + e + 1];
    float w0 = w_s[start + e];
    float w1 = w_s[start + e + 1];
    float g0 = G[s0 * H2 + dim];
    float g1 = G[s1 * H2 + dim];
    acc = fmaf(w0, g0, acc);
    acc = fmaf(w1, g1, acc);
  }
  if (e < n) {
    int s0 = src_s[start + e];
    acc = fmaf(w_s[start + e], G[s0 * H2 + dim], acc);
  }
  out[gi] = fmaf(acc, dinv_in[node], b2[dim]);
}

extern "C" void kernel_launch(void* const* d_in, const int* in_sizes, int n_in,
                              void* d_out, int out_size, void* d_ws, size_t ws_size,
                              hipStream_t stream) {
  const float* feature = (const float*)d_in[0];
  const int* src = (const int*)d_in[1];
  const int* dst = (const int*)d_in[2];
  const float* edge_w = (const float*)d_in[3];
  const float* W1 = (const float*)d_in[4];
  const float* b1 = (const float*)d_in[5];
  const float* W2 = (const float*)d_in[6];
  const float* b2 = (const float*)d_in[7];
  float* out = (float*)d_out;

  char* wsb = (char*)d_ws;
  int* cnt_dst = (int*)(wsb + (size_t)0 * 4);
  int* cnt_src = (int*)(wsb + (size_t)50000 * 4);
  int* cursor = (int*)(wsb + (size_t)100000 * 4);
  int* partials = (int*)(wsb + (size_t)150000 * 4);
  int* row_start = (int*)(wsb + (size_t)150256 * 4);
  float* dinv_in = (float*)(wsb + (size_t)200256 * 4);
  float* dinv_out = (float*)(wsb + (size_t)250256 * 4);
  int* src_s = (int*)(wsb + (size_t)300256 * 4);
  float* w_s = (float*)(wsb + (size_t)1100256 * 4);
  float* h = (float*)(wsb + (size_t)1900256 * 4);
  float* g2 = (float*)(wsb + (size_t)11900256 * 4);

  // zero cnt_dst, cnt_src, cursor (contiguous 150000 ints)
  hipMemsetAsync(wsb, 0, (size_t)150000 * 4, stream);

  k_count<<<(N_EDGES + 255) / 256, 256, 0, stream>>>(src, dst, cnt_src, cnt_dst);
  k_scan_block<<<NB_SCAN, 256, 0, stream>>>(cnt_dst, row_start, partials);
  k_scan_partials<<<1, 256, 0, stream>>>(partials);
  k_scan_add<<<NB_SCAN, 256, 0, stream>>>(cnt_dst, cnt_src, partials, row_start,
                                          dinv_in, dinv_out);
  k_fill<<<(N_EDGES + 255) / 256, 256, 0, stream>>>(src, dst, edge_w, row_start,
                                                    cursor, src_s, w_s);

  dim3 g1((N_NODES + BM - 1) / BM, (H1 + BN - 1) / BN);
  k_gemm1<<<g1, 256, 0, stream>>>(feature, W1, dinv_out, h);

  k_layer1<<<N_NODES / 4, 256, 0, stream>>>(row_start, cnt_dst, src_s, w_s, h,
                                            dinv_in, dinv_out, b1, W2, g2);
  k_agg2_final<<<(N_NODES * H2 + 255) / 256, 256, 0, stream>>>(
      row_start, cnt_dst, src_s, w_s, g2, dinv_in, b2, out);
}

// Round 3
// 580.408 us; speedup vs baseline: 5.4299x; 1.2349x over previous
//
#include <hip/hip_runtime.h>

#define N_NODES 50000
#define N_EDGES 800000
#define F_IN 768
#define H1 200
#define H2 20
#define NB_SCAN 196  // ceil(50000/256)

typedef unsigned short ushort_t;
typedef __attribute__((ext_vector_type(8))) short bf16x8;
typedef __attribute__((ext_vector_type(4))) float f32x4;

// ---------------------------------------------------------------------------
// Workspace layout (byte offsets):
//   0         cnt_dst   int[50000]   (zeroed)
//   200000    cnt_src   int[50000]   (zeroed)
//   400000    cursor    int[50000]   (zeroed)
//   600000    partials  int[256]
//   601024    row_start int[50000]
//   801024    dinv_in   f32[50000]
//   1001024   dinv_out  f32[50000]
//   1201024   src_s     int[800000]
//   4401024   w_s       f32[800000]
//   7601024   h         f32[10000000]
//   47601024  g2        f32[1000000]
//   51601024  W1sH      u16[208*768]
//   51920512  W1sL      u16[208*768]
// total ~52.3 MB
// ---------------------------------------------------------------------------

// ---------------- histogram of degrees (int atomics) -----------------------
__global__ __launch_bounds__(256) void k_count(const int* __restrict__ src,
                                               const int* __restrict__ dst,
                                               int* __restrict__ cnt_src,
                                               int* __restrict__ cnt_dst) {
  int i = blockIdx.x * 256 + threadIdx.x;
  if (i < N_EDGES) {
    atomicAdd(&cnt_src[src[i]], 1);
    atomicAdd(&cnt_dst[dst[i]], 1);
  }
}

// ---------------- 2-level exclusive scan of cnt_dst -> row_start -----------
__global__ __launch_bounds__(256) void k_scan_block(const int* __restrict__ cnt_dst,
                                                    int* __restrict__ row_start,
                                                    int* __restrict__ partials) {
  __shared__ int sm[256];
  int i = blockIdx.x * 256 + threadIdx.x;
  int v = (i < N_NODES) ? cnt_dst[i] : 0;
  sm[threadIdx.x] = v;
  __syncthreads();
#pragma unroll
  for (int off = 1; off < 256; off <<= 1) {
    int t = (threadIdx.x >= off) ? sm[threadIdx.x - off] : 0;
    __syncthreads();
    sm[threadIdx.x] += t;
    __syncthreads();
  }
  if (i < N_NODES) row_start[i] = sm[threadIdx.x] - v;  // exclusive
  if (threadIdx.x == 255) partials[blockIdx.x] = sm[255];
}

__global__ __launch_bounds__(256) void k_scan_partials(int* __restrict__ partials) {
  __shared__ int sm[256];
  int v = (threadIdx.x < NB_SCAN) ? partials[threadIdx.x] : 0;
  sm[threadIdx.x] = v;
  __syncthreads();
#pragma unroll
  for (int off = 1; off < 256; off <<= 1) {
    int t = (threadIdx.x >= off) ? sm[threadIdx.x - off] : 0;
    __syncthreads();
    sm[threadIdx.x] += t;
    __syncthreads();
  }
  partials[threadIdx.x] = sm[threadIdx.x] - v;
}

__global__ __launch_bounds__(256) void k_scan_add(const int* __restrict__ cnt_dst,
                                                  const int* __restrict__ cnt_src,
                                                  const int* __restrict__ partials,
                                                  int* __restrict__ row_start,
                                                  float* __restrict__ dinv_in,
                                                  float* __restrict__ dinv_out) {
  int i = blockIdx.x * 256 + threadIdx.x;
  if (i < N_NODES) {
    row_start[i] += partials[blockIdx.x];
    dinv_in[i] = rsqrtf(fmaxf((float)cnt_dst[i], 1.f));
    dinv_out[i] = rsqrtf(fmaxf((float)cnt_src[i], 1.f));
  }
}

// ---------------- fill dst-sorted edge arrays -------------------------------
__global__ __launch_bounds__(256) void k_fill(const int* __restrict__ src,
                                              const int* __restrict__ dst,
                                              const float* __restrict__ ew,
                                              const int* __restrict__ row_start,
                                              int* __restrict__ cursor,
                                              int* __restrict__ src_s,
                                              float* __restrict__ w_s) {
  int e = blockIdx.x * 256 + threadIdx.x;
  if (e < N_EDGES) {
    int d = dst[e];
    int pos = atomicAdd(&cursor[d], 1);
    int idx = row_start[d] + pos;
    src_s[idx] = src[e];
    w_s[idx] = ew[e];
  }
}

// ---------------- split W1 into transposed bf16 hi/lo ----------------------
// WH/WL layout: [208 cols][768 k], cols 200..207 zero-padded.
__global__ __launch_bounds__(256) void k_splitW(const float* __restrict__ W1,
                                                ushort_t* __restrict__ WH,
                                                ushort_t* __restrict__ WL) {
  int idx = blockIdx.x * 256 + threadIdx.x;
  if (idx >= 208 * F_IN) return;
  int col = idx / F_IN, k = idx % F_IN;
  float f = (col < H1) ? W1[k * H1 + col] : 0.f;
  unsigned b = __float_as_uint(f);
  unsigned h = b >> 16;
  float lo = f - __uint_as_float(h << 16);
  WH[idx] = (ushort_t)h;
  WL[idx] = (ushort_t)(__float_as_uint(lo) >> 16);
}

// ---------------- GEMM1 via split-bf16 MFMA --------------------------------
// h = (feat @ W1) * dinv_out[:,None]   (row scaling commutes to epilogue)
// BM=64 rows/block, full N=200 (13 tiles of 16), BK=32, 4 waves.
// Wave w computes rows [bm+w*16, +16) x all 13 N-tiles (acc 13 x f32x4).
#define NT 13

__global__ __launch_bounds__(256) void k_gemm1_mfma(
    const float* __restrict__ A,      // feature [50000][768]
    const ushort_t* __restrict__ BH,  // [208][768] bf16-hi of W1^T
    const ushort_t* __restrict__ BL,  // [208][768] bf16-lo
    const float* __restrict__ dinv_out,
    float* __restrict__ H) {          // [50000][200]
  __shared__ ushort_t AsH[64][32];
  __shared__ ushort_t AsL[64][32];
  __shared__ ushort_t BsH[NT][16][32];
  __shared__ ushort_t BsL[NT][16][32];

  const int t = threadIdx.x;
  const int wid = t >> 6;
  const int lane = t & 63;
  const int bm = blockIdx.x * 64;
  const int arow = t >> 2;         // 0..63 (A staging row)
  const int akq = (t & 3) * 8;     // A staging k-offset
  const int frow = lane & 15;      // fragment row/col
  const int fkq = (lane >> 4) * 8; // fragment k-offset

  f32x4 acc[NT];
#pragma unroll
  for (int i = 0; i < NT; ++i) acc[i] = (f32x4)(0.f);

  const int agr = bm + arow;
  const float* __restrict__ arowp = &A[(size_t)agr * F_IN + akq];

  for (int k0 = 0; k0 < F_IN; k0 += 32) {
    // ---- load A 8 floats/thread, convert to bf16 hi/lo in regs ----
    float4 v0 = make_float4(0.f, 0.f, 0.f, 0.f), v1 = v0;
    if (agr < N_NODES) {
      v0 = *(const float4*)&arowp[k0];
      v1 = *(const float4*)&arowp[k0 + 4];
    }
    float fv[8] = {v0.x, v0.y, v0.z, v0.w, v1.x, v1.y, v1.z, v1.w};
    unsigned hp[4], lp[4];
#pragma unroll
    for (int i = 0; i < 4; ++i) {
      unsigned b0 = __float_as_uint(fv[2 * i]);
      unsigned b1 = __float_as_uint(fv[2 * i + 1]);
      unsigned h0 = b0 >> 16, h1 = b1 >> 16;
      float lo0 = fv[2 * i] - __uint_as_float(h0 << 16);
      float lo1 = fv[2 * i + 1] - __uint_as_float(h1 << 16);
      hp[i] = h0 | (h1 << 16);
      lp[i] = (__float_as_uint(lo0) >> 16) | (__float_as_uint(lo1) & 0xffff0000u);
    }

    __syncthreads();  // previous iteration's fragment reads done

    // ---- A tile to LDS ----
    *(uint4*)&AsH[arow][akq] = make_uint4(hp[0], hp[1], hp[2], hp[3]);
    *(uint4*)&AsL[arow][akq] = make_uint4(lp[0], lp[1], lp[2], lp[3]);

    // ---- B tiles to LDS via global_load_lds (16B/lane, linear dest) ----
    // lane l covers col=l>>2, k-quarter=l&3 of a [16][32] bf16 tile (1KB).
    {
      int bcol = lane >> 2;
      int bko = (lane & 3) * 8;
      for (int nt = wid; nt < NT; nt += 4) {
        const ushort_t* gh = &BH[(size_t)(nt * 16 + bcol) * F_IN + k0 + bko];
        const ushort_t* gl = &BL[(size_t)(nt * 16 + bcol) * F_IN + k0 + bko];
        __builtin_amdgcn_global_load_lds(gh, &BsH[nt][0][0], 16, 0, 0);
        __builtin_amdgcn_global_load_lds(gl, &BsL[nt][0][0], 16, 0, 0);
      }
    }

    __syncthreads();  // LDS writes + async B loads visible

    // ---- fragments + MFMA ----
    bf16x8 aH = *(const bf16x8*)&AsH[wid * 16 + frow][fkq];
    bf16x8 aL = *(const bf16x8*)&AsL[wid * 16 + frow][fkq];
#pragma unroll
    for (int nt = 0; nt < NT; ++nt) {
      bf16x8 bH = *(const bf16x8*)&BsH[nt][frow][fkq];
      bf16x8 bL = *(const bf16x8*)&BsL[nt][frow][fkq];
      acc[nt] = __builtin_amdgcn_mfma_f32_16x16x32_bf16(aH, bH, acc[nt], 0, 0, 0);
      acc[nt] = __builtin_amdgcn_mfma_f32_16x16x32_bf16(aH, bL, acc[nt], 0, 0, 0);
      acc[nt] = __builtin_amdgcn_mfma_f32_16x16x32_bf16(aL, bH, acc[nt], 0, 0, 0);
    }
  }

  // ---- epilogue: D[i][j] -> row = wid*16 + (lane>>4)*4 + r, col = lane&15 ----
  const int r0 = bm + wid * 16 + (lane >> 4) * 4;
  float dsc[4];
#pragma unroll
  for (int r = 0; r < 4; ++r)
    dsc[r] = (r0 + r < N_NODES) ? dinv_out[r0 + r] : 0.f;
#pragma unroll
  for (int nt = 0; nt < NT; ++nt) {
    int gc = nt * 16 + (lane & 15);
    if (gc < H1) {
#pragma unroll
      for (int r = 0; r < 4; ++r) {
        int gr = r0 + r;
        if (gr < N_NODES) H[(size_t)gr * H1 + gc] = acc[nt][r] * dsc[r];
      }
    }
  }
}

// ---------------- layer1 fused: gather-agg + post + GEMM2 ------------------
__global__ __launch_bounds__(256) void k_layer1(
    const int* __restrict__ row_start, const int* __restrict__ cnt,
    const int* __restrict__ src_s, const float* __restrict__ w_s,
    const float* __restrict__ H, const float* __restrict__ dinv_in,
    const float* __restrict__ dinv_out, const float* __restrict__ b1,
    const float* __restrict__ W2, float* __restrict__ G) {
  __shared__ float Tsm[4][H1];
  const int wid = threadIdx.x >> 6;
  const int lane = threadIdx.x & 63;
  const int node = __builtin_amdgcn_readfirstlane(blockIdx.x * 4 + wid);
  const int start = __builtin_amdgcn_readfirstlane(row_start[node]);
  const int n = __builtin_amdgcn_readfirstlane(cnt[node]);
  const float4* __restrict__ Hv = (const float4*)H;
  const bool act = lane < (H1 / 4);
  float4 acc = make_float4(0.f, 0.f, 0.f, 0.f);

  int e = 0;
  for (; e + 2 <= n; e += 2) {
    int s0 = src_s[start + e];
    int s1 = src_s[start + e + 1];
    float w0 = w_s[start + e];
    float w1 = w_s[start + e + 1];
    if (act) {
      float4 v0 = Hv[s0 * (H1 / 4) + lane];
      float4 v1 = Hv[s1 * (H1 / 4) + lane];
      acc.x = fmaf(w0, v0.x, acc.x);
      acc.y = fmaf(w0, v0.y, acc.y);
      acc.z = fmaf(w0, v0.z, acc.z);
      acc.w = fmaf(w0, v0.w, acc.w);
      acc.x = fmaf(w1, v1.x, acc.x);
      acc.y = fmaf(w1, v1.y, acc.y);
      acc.z = fmaf(w1, v1.z, acc.z);
      acc.w = fmaf(w1, v1.w, acc.w);
    }
  }
  if (e < n) {
    int s0 = src_s[start + e];
    float w0 = w_s[start + e];
    if (act) {
      float4 v0 = Hv[s0 * (H1 / 4) + lane];
      acc.x = fmaf(w0, v0.x, acc.x);
      acc.y = fmaf(w0, v0.y, acc.y);
      acc.z = fmaf(w0, v0.z, acc.z);
      acc.w = fmaf(w0, v0.w, acc.w);
    }
  }

  if (act) {
    float di = dinv_in[node];
    float dn = dinv_out[node];
    float4 bb = ((const float4*)b1)[lane];
    float4 r;
    r.x = fmaxf(fmaf(acc.x, di, bb.x), 0.f) * dn;
    r.y = fmaxf(fmaf(acc.y, di, bb.y), 0.f) * dn;
    r.z = fmaxf(fmaf(acc.z, di, bb.z), 0.f) * dn;
    r.w = fmaxf(fmaf(acc.w, di, bb.w), 0.f) * dn;
    *(float4*)&Tsm[wid][lane * 4] = r;
  }
  __syncthreads();

  if (lane < H2) {
    float a = 0.f;
#pragma unroll 8
    for (int d = 0; d < H1; ++d) a = fmaf(Tsm[wid][d], W2[d * H2 + lane], a);
    G[node * H2 + lane] = a;
  }
}

// ---------------- layer2: gather-agg + bias (no atomics) -------------------
__global__ __launch_bounds__(256) void k_agg2_final(
    const int* __restrict__ row_start, const int* __restrict__ cnt,
    const int* __restrict__ src_s, const float* __restrict__ w_s,
    const float* __restrict__ G, const float* __restrict__ dinv_in,
    const float* __restrict__ b2, float* __restrict__ out) {
  int gi = blockIdx.x * 256 + threadIdx.x;
  if (gi >= N_NODES * H2) return;
  int node = gi / H2;
  int dim = gi % H2;
  int start = row_start[node];
  int n = cnt[node];
  float acc = 0.f;
  int e = 0;
  for (; e + 2 <= n; e += 2) {
    int s0 = src_s[start + e];
    int s1 = src_s[start + e + 1];
    float w0 = w_s[start + e];
    float w1 = w_s[start + e + 1];
    float g0 = G[s0 * H2 + dim];
    float g1 = G[s1 * H2 + dim];
    acc = fmaf(w0, g0, acc);
    acc = fmaf(w1, g1, acc);
  }
  if (e < n) {
    int s0 = src_s[start + e];
    acc = fmaf(w_s[start + e], G[s0 * H2 + dim], acc);
  }
  out[gi] = fmaf(acc, dinv_in[node], b2[dim]);
}

extern "C" void kernel_launch(void* const* d_in, const int* in_sizes, int n_in,
                              void* d_out, int out_size, void* d_ws, size_t ws_size,
                              hipStream_t stream) {
  const float* feature = (const float*)d_in[0];
  const int* src = (const int*)d_in[1];
  const int* dst = (const int*)d_in[2];
  const float* edge_w = (const float*)d_in[3];
  const float* W1 = (const float*)d_in[4];
  const float* b1 = (const float*)d_in[5];
  const float* W2 = (const float*)d_in[6];
  const float* b2 = (const float*)d_in[7];
  float* out = (float*)d_out;

  char* wsb = (char*)d_ws;
  int* cnt_dst = (int*)(wsb + 0);
  int* cnt_src = (int*)(wsb + 200000);
  int* cursor = (int*)(wsb + 400000);
  int* partials = (int*)(wsb + 600000);
  int* row_start = (int*)(wsb + 601024);
  float* dinv_in = (float*)(wsb + 801024);
  float* dinv_out = (float*)(wsb + 1001024);
  int* src_s = (int*)(wsb + 1201024);
  float* w_s = (float*)(wsb + 4401024);
  float* h = (float*)(wsb + 7601024);
  float* g2 = (float*)(wsb + 47601024);
  ushort_t* W1sH = (ushort_t*)(wsb + 51601024);
  ushort_t* W1sL = (ushort_t*)(wsb + 51920512);

  // zero cnt_dst, cnt_src, cursor
  hipMemsetAsync(wsb, 0, 600000, stream);

  k_count<<<(N_EDGES + 255) / 256, 256, 0, stream>>>(src, dst, cnt_src, cnt_dst);
  k_scan_block<<<NB_SCAN, 256, 0, stream>>>(cnt_dst, row_start, partials);
  k_scan_partials<<<1, 256, 0, stream>>>(partials);
  k_scan_add<<<NB_SCAN, 256, 0, stream>>>(cnt_dst, cnt_src, partials, row_start,
                                          dinv_in, dinv_out);
  k_fill<<<(N_EDGES + 255) / 256, 256, 0, stream>>>(src, dst, edge_w, row_start,
                                                    cursor, src_s, w_s);
  k_splitW<<<(208 * F_IN + 255) / 256, 256, 0, stream>>>(W1, W1sH, W1sL);

  k_gemm1_mfma<<<(N_NODES + 63) / 64, 256, 0, stream>>>(feature, W1sH, W1sL,
                                                        dinv_out, h);

  k_layer1<<<N_NODES / 4, 256, 0, stream>>>(row_start, cnt_dst, src_s, w_s, h,
                                            dinv_in, dinv_out, b1, W2, g2);
  k_agg2_final<<<(N_NODES * H2 + 255) / 256, 256, 0, stream>>>(
      row_start, cnt_dst, src_s, w_s, g2, dinv_in, b2, out);
}